// Round 1
// baseline (2205.666 us; speedup 1.0000x reference)
//
#include <hip/hip_runtime.h>
#include <math.h>

#define NB   16      // batch
#define NM   4096    // preds per image
#define NT   512     // targets per image
#define CAP  16      // max stored candidates per row (overflow -> exact fallback)
#define IOU_THR 0.1f
#define EPSG 1e-7f

// ---------------------------------------------------------------------------
// Kernel 1: per pred-row candidate list (targets with IoU > 0.1), ascending j.
// One wave (64 lanes) per row; 8 targets per lane.
// ---------------------------------------------------------------------------
__global__ __launch_bounds__(256) void cand_kernel(
    const float4* __restrict__ pred, const float4* __restrict__ tgt,
    int* __restrict__ counts, float2* __restrict__ cands)
{
    int gtid = blockIdx.x * blockDim.x + threadIdx.x;
    int wid  = gtid >> 6;           // global row id in [0, NB*NM)
    int lane = threadIdx.x & 63;
    int b = wid >> 12;              // NM = 4096

    float4 p = pred[wid];
    float area_p = (p.z - p.x) * (p.w - p.y);
    const float4* t_img = tgt + b * NT;

    int base = 0;
    #pragma unroll
    for (int pass = 0; pass < NT / 64; ++pass) {
        int j = (pass << 6) + lane;
        float4 t = t_img[j];
        float area_t = (t.z - t.x) * (t.w - t.y);
        float w = fmaxf(fminf(p.z, t.z) - fmaxf(p.x, t.x), 0.f);
        float h = fmaxf(fminf(p.w, t.w) - fmaxf(p.y, t.y), 0.f);
        float inter = w * h;
        float uni   = (area_p + area_t) - inter;   // same association as reference
        float iou   = inter / uni;
        bool q = iou > IOU_THR;
        unsigned long long m = __ballot(q);
        if (q) {
            int off = base + __popcll(m & ((1ull << lane) - 1ull));
            if (off < CAP)
                cands[(size_t)wid * CAP + off] = make_float2(iou, __int_as_float(j));
        }
        base += __popcll(m);
    }
    if (lane == 0) counts[wid] = base;   // may exceed CAP -> fallback flag
}

// ---------------------------------------------------------------------------
// Kernel 2: sequential greedy match + GIoU accumulation. One wave per image.
// used mask is register-resident: lane l owns bits for targets [8l, 8l+8).
// ---------------------------------------------------------------------------
__global__ __launch_bounds__(64) void scan_kernel(
    const float4* __restrict__ pred, const float4* __restrict__ tgt,
    const int* __restrict__ counts, const float2* __restrict__ cands,
    float* __restrict__ per_img)
{
    __shared__ float4 t_lds[NT];        // 8 KB
    __shared__ float2 c_lds[64 * CAP];  // 8 KB, one chunk of candidate lists

    const int b    = blockIdx.x;
    const int lane = threadIdx.x;

    // stage targets for this image
    #pragma unroll
    for (int r = 0; r < NT / 64; ++r)
        t_lds[r * 64 + lane] = tgt[b * NT + r * 64 + lane];

    unsigned used_mask = 0u;
    float loss_sum = 0.f;
    int   cnt = 0;

    // prefetch chunk 0 into registers
    int    stage_cnt = counts[b * NM + lane];
    float4 stage_p   = pred[b * NM + lane];
    float2 stage_c[CAP];
    {
        const float2* src = cands + (size_t)(b * NM) * CAP;
        #pragma unroll
        for (int rr = 0; rr < CAP; ++rr) stage_c[rr] = src[rr * 64 + lane];
    }

    for (int chunk = 0; chunk < NM / 64; ++chunk) {
        __syncthreads();                      // previous chunk's LDS reads done
        #pragma unroll
        for (int rr = 0; rr < CAP; ++rr) c_lds[rr * 64 + lane] = stage_c[rr];
        int    cur_cnt = stage_cnt;
        float4 cur_p   = stage_p;
        __syncthreads();                      // LDS writes visible

        if (chunk + 1 < NM / 64) {            // prefetch next chunk (latency hides)
            int base_row = b * NM + (chunk + 1) * 64;
            stage_cnt = counts[base_row + lane];
            stage_p   = pred[base_row + lane];
            const float2* src = cands + (size_t)base_row * CAP;
            #pragma unroll
            for (int rr = 0; rr < CAP; ++rr) stage_c[rr] = src[rr * 64 + lane];
        }

        for (int r = 0; r < 64; ++r) {
            int c = __shfl(cur_cnt, r);       // wave-uniform
            if (c == 0) continue;

            float4 p;
            p.x = __shfl(cur_p.x, r); p.y = __shfl(cur_p.y, r);
            p.z = __shfl(cur_p.z, r); p.w = __shfl(cur_p.w, r);

            float v; int bj;
            if (c <= CAP) {
                // all shuffles full-wave (no divergence around cross-lane ops)
                float2 e = c_lds[r * CAP + (lane & (CAP - 1))];
                int j  = __float_as_int(e.y);
                int jm = j & (NT - 1);        // clamp garbage lanes for safety
                unsigned um = __shfl(used_mask, jm >> 3);
                bool have = (lane < c) && !((um >> (jm & 7)) & 1u);
                v  = have ? e.x : -INFINITY;
                bj = have ? j   : 0x7fffffff;
                #pragma unroll
                for (int off = 1; off < 16; off <<= 1) {
                    float ov = __shfl_xor(v, off);
                    int   oj = __shfl_xor(bj, off);
                    if (ov > v || (ov == v && oj < bj)) { v = ov; bj = oj; }
                }
                v  = __shfl(v, 0);
                bj = __shfl(bj, 0);
            } else {
                // overflow fallback: exact masked argmax over all 512 targets
                float area_p = (p.z - p.x) * (p.w - p.y);
                v = -INFINITY; bj = 0x7fffffff;
                #pragma unroll
                for (int pass = 0; pass < NT / 64; ++pass) {
                    int j = (pass << 6) + lane;      // ascending j per lane
                    float4 t = t_lds[j];
                    float area_t = (t.z - t.x) * (t.w - t.y);
                    float w = fmaxf(fminf(p.z, t.z) - fmaxf(p.x, t.x), 0.f);
                    float h = fmaxf(fminf(p.w, t.w) - fmaxf(p.y, t.y), 0.f);
                    float inter = w * h;
                    float iou = inter / ((area_p + area_t) - inter);
                    unsigned um = __shfl(used_mask, j >> 3);
                    bool fr = !((um >> (j & 7)) & 1u);
                    if (fr && iou > v) { v = iou; bj = j; }   // strict > keeps lowest j
                }
                #pragma unroll
                for (int off = 1; off < 64; off <<= 1) {
                    float ov = __shfl_xor(v, off);
                    int   oj = __shfl_xor(bj, off);
                    if (ov > v || (ov == v && oj < bj)) { v = ov; bj = oj; }
                }
            }

            if (v > IOU_THR) {                 // wave-uniform valid match
                if (lane == (bj >> 3)) used_mask |= 1u << (bj & 7);
                float4 t = t_lds[bj];          // uniform broadcast read
                float inter = fmaxf(fminf(p.z, t.z) - fmaxf(p.x, t.x), 0.f) *
                              fmaxf(fminf(p.w, t.w) - fmaxf(p.y, t.y), 0.f);
                float area_p = (p.z - p.x) * (p.w - p.y);
                float area_t = (t.z - t.x) * (t.w - t.y);
                float uni = area_p + area_t - inter;
                float iou = inter / (uni + EPSG);
                float enc = (fmaxf(p.z, t.z) - fminf(p.x, t.x)) *
                            (fmaxf(p.w, t.w) - fminf(p.y, t.y));
                float giou = iou - (enc - uni) / (enc + EPSG);
                loss_sum += 1.f - giou;
                cnt += 1;
            }
        }
    }

    if (lane == 0) per_img[b] = (cnt > 0) ? loss_sum / (float)cnt : 0.f;
}

// ---------------------------------------------------------------------------
// Kernel 3: mean over images -> scalar output. Deterministic (no atomics).
// ---------------------------------------------------------------------------
__global__ void reduce_kernel(const float* __restrict__ per_img,
                              float* __restrict__ out)
{
    if (threadIdx.x == 0 && blockIdx.x == 0) {
        float s = 0.f;
        for (int i = 0; i < NB; ++i) s += per_img[i];
        out[0] = s / (float)NB;
    }
}

extern "C" void kernel_launch(void* const* d_in, const int* in_sizes, int n_in,
                              void* d_out, int out_size, void* d_ws, size_t ws_size,
                              hipStream_t stream)
{
    const float4* pred = (const float4*)d_in[0];   // [16,4096,4] f32
    const float4* tgt  = (const float4*)d_in[1];   // [16,512,4]  f32

    char* ws = (char*)d_ws;
    // layout: counts [NB*NM] i32 | cands [NB*NM*CAP] float2 | per_img [NB] f32
    int*    counts  = (int*)ws;
    size_t  off1    = (size_t)NB * NM * sizeof(int);            // 256 KB
    float2* cands   = (float2*)(ws + off1);
    size_t  off2    = off1 + (size_t)NB * NM * CAP * sizeof(float2); // +8 MB
    float*  per_img = (float*)(ws + off2);

    cand_kernel<<<NB * NM / 4, 256, 0, stream>>>(pred, tgt, counts, cands);
    scan_kernel<<<NB, 64, 0, stream>>>(pred, tgt, counts, cands, per_img);
    reduce_kernel<<<1, 64, 0, stream>>>(per_img, (float*)d_out);
}

// Round 2
// 167.676 us; speedup vs baseline: 13.1544x; 13.1544x over previous
//
#include <hip/hip_runtime.h>
#include <math.h>

#define NB   16      // batch
#define NM   4096    // preds per image
#define NT   512     // targets per image
#define CAP  16      // max stored candidates per row (overflow -> exact fallback)
#define IOU_THR 0.1f
#define EPSG 1e-7f
#define NROWS (NB*NM)

// ---------------------------------------------------------------------------
// Kernel 1: per pred-row candidate list (targets with IoU > 0.1), ascending j.
// One wave (64 lanes) per row; 8 targets per lane. Candidates stored
// TRANSPOSED: cands[e*NROWS + row] so kernel-2 loads are coalesced.
// ---------------------------------------------------------------------------
__global__ __launch_bounds__(256) void cand_kernel(
    const float4* __restrict__ pred, const float4* __restrict__ tgt,
    int* __restrict__ counts, float2* __restrict__ cands)
{
    int gtid = blockIdx.x * blockDim.x + threadIdx.x;
    int wid  = gtid >> 6;           // global row id in [0, NROWS)
    int lane = threadIdx.x & 63;
    int b = wid >> 12;              // NM = 4096

    float4 p = pred[wid];
    float area_p = (p.z - p.x) * (p.w - p.y);
    const float4* t_img = tgt + b * NT;

    int base = 0;
    #pragma unroll
    for (int pass = 0; pass < NT / 64; ++pass) {
        int j = (pass << 6) + lane;
        float4 t = t_img[j];
        float area_t = (t.z - t.x) * (t.w - t.y);
        float w = fmaxf(fminf(p.z, t.z) - fmaxf(p.x, t.x), 0.f);
        float h = fmaxf(fminf(p.w, t.w) - fmaxf(p.y, t.y), 0.f);
        float inter = w * h;
        float uni   = (area_p + area_t) - inter;   // same association as reference
        float iou   = inter / uni;
        bool q = iou > IOU_THR;
        unsigned long long m = __ballot(q);
        if (q) {
            int off = base + __popcll(m & ((1ull << lane) - 1ull));
            if (off < CAP)
                cands[(size_t)off * NROWS + wid] = make_float2(iou, __int_as_float(j));
        }
        base += __popcll(m);
    }
    if (lane == 0) counts[wid] = base;   // may exceed CAP -> fallback flag
}

// ---------------------------------------------------------------------------
// Kernel 2: speculative window-parallel greedy match. One wave per image.
// Lane r owns row (win*64 + r): candidates in registers, local argmax vs the
// LDS used-mask, LDS claim[] atomicMin resolves conflicts; commit everything
// below the first loser (provably identical to the serial greedy).
// ---------------------------------------------------------------------------
__global__ __launch_bounds__(64) void scan_kernel(
    const float4* __restrict__ pred, const float4* __restrict__ tgt,
    const int* __restrict__ counts, const float2* __restrict__ cands,
    float* __restrict__ per_img)
{
    __shared__ float4  t_lds[NT];        // 8 KB
    __shared__ unsigned used_w[NT / 32]; // 512-bit used mask
    __shared__ unsigned claim[NT];       // 2 KB, monotone (abs row idx), no reset

    const int b    = blockIdx.x;
    const int lane = threadIdx.x;

    #pragma unroll
    for (int r = 0; r < NT / 64; ++r)
        t_lds[r * 64 + lane] = tgt[b * NT + r * 64 + lane];
    if (lane < NT / 32) used_w[lane] = 0u;
    #pragma unroll
    for (int r = 0; r < NT / 64; ++r) claim[r * 64 + lane] = 0xFFFFFFFFu;
    __syncthreads();

    float loss_sum = 0.f;
    int   mcnt = 0;

    // load window 0 into registers (lane = row within window)
    int cur_cnt; float4 cur_p; float2 cur_c[CAP];
    {
        int row = b * NM + lane;
        cur_cnt = counts[row];
        cur_p   = pred[row];
        #pragma unroll
        for (int e = 0; e < CAP; ++e) cur_c[e] = cands[(size_t)e * NROWS + row];
    }

    for (int win = 0; win < NM / 64; ++win) {
        // prefetch next window early; latency hides under the rounds below
        int nxt_cnt; float4 nxt_p; float2 nxt_c[CAP];
        {
            int w2  = (win + 1 < NM / 64) ? win + 1 : 0;   // clamp (dummy last)
            int row = b * NM + w2 * 64 + lane;
            nxt_cnt = counts[row];
            nxt_p   = pred[row];
            #pragma unroll
            for (int e = 0; e < CAP; ++e) nxt_c[e] = cands[(size_t)e * NROWS + row];
        }

        const unsigned abs_row = (unsigned)(win * 64 + lane);
        bool resolved = (cur_cnt == 0);

        while (true) {
            unsigned long long unres = __ballot(!resolved);
            if (!unres) break;

            bool ovf = (!resolved) && (cur_cnt > CAP);
            int best_j = -1; float best_v = -1.f;
            if (!resolved && !ovf) {
                #pragma unroll
                for (int e = 0; e < CAP; ++e) {
                    int j = __float_as_int(cur_c[e].y) & (NT - 1);
                    unsigned wbits = used_w[j >> 5];        // LDS broadcast-ish read
                    bool ok = (e < cur_cnt) && !((wbits >> (j & 31)) & 1u);
                    float v = cur_c[e].x;
                    if (ok && v > best_v) { best_v = v; best_j = j; } // strict >: lowest j on ties
                }
            }
            bool has_choice = (!resolved) && (!ovf) && (best_j >= 0);
            // no-choice rows can never gain a match (commits only remove targets)
            if (!resolved && !ovf && best_j < 0) resolved = true;

            if (has_choice) atomicMin(&claim[best_j], abs_row);
            bool loser = false;
            if (has_choice) loser = (claim[best_j] != abs_row);

            unsigned long long badmask = __ballot(loser || ovf);
            int F = badmask ? (__ffsll(badmask) - 1) : 64;

            bool commit = has_choice && (lane < F);
            if (commit) {
                atomicOr(&used_w[best_j >> 5], 1u << (best_j & 31));
                float4 t = t_lds[best_j];
                float4 p = cur_p;
                float inter = fmaxf(fminf(p.z, t.z) - fmaxf(p.x, t.x), 0.f) *
                              fmaxf(fminf(p.w, t.w) - fmaxf(p.y, t.y), 0.f);
                float area_p = (p.z - p.x) * (p.w - p.y);
                float area_t = (t.z - t.x) * (t.w - t.y);
                float uni = area_p + area_t - inter;
                float iou = inter / (uni + EPSG);
                float enc = (fmaxf(p.z, t.z) - fminf(p.x, t.x)) *
                            (fmaxf(p.w, t.w) - fminf(p.y, t.y));
                float giou = iou - (enc - uni) / (enc + EPSG);
                loss_sum += 1.f - giou;
                mcnt++;
                resolved = true;
            }

            // exact fallback: next unresolved row has >CAP candidates (≈ never)
            if (F < 64) {
                unsigned long long ovfm = __ballot(ovf);
                if ((ovfm >> F) & 1ull) {
                    float px = __shfl(cur_p.x, F), py = __shfl(cur_p.y, F);
                    float pz = __shfl(cur_p.z, F), pw = __shfl(cur_p.w, F);
                    float area_p = (pz - px) * (pw - py);
                    float v = -1.f; int bj = NT;
                    #pragma unroll
                    for (int pass = 0; pass < NT / 64; ++pass) {
                        int j = (pass << 6) + lane;
                        float4 t = t_lds[j];
                        unsigned wbits = used_w[j >> 5];   // sees this round's commits
                        bool freej = !((wbits >> (j & 31)) & 1u);
                        float area_t = (t.z - t.x) * (t.w - t.y);
                        float w = fmaxf(fminf(pz, t.z) - fmaxf(px, t.x), 0.f);
                        float h = fmaxf(fminf(pw, t.w) - fmaxf(py, t.y), 0.f);
                        float inter = w * h;
                        float iou = inter / ((area_p + area_t) - inter);
                        if (freej && iou > v) { v = iou; bj = j; }
                    }
                    #pragma unroll
                    for (int off = 1; off < 64; off <<= 1) {
                        float ov = __shfl_xor(v, off);
                        int   oj = __shfl_xor(bj, off);
                        if (ov > v || (ov == v && oj < bj)) { v = ov; bj = oj; }
                    }
                    if (v > IOU_THR) {
                        if (lane == 0) atomicOr(&used_w[bj >> 5], 1u << (bj & 31));
                        if (lane == F) {
                            float4 t = t_lds[bj];
                            float4 p = cur_p;
                            float inter = fmaxf(fminf(p.z, t.z) - fmaxf(p.x, t.x), 0.f) *
                                          fmaxf(fminf(p.w, t.w) - fmaxf(p.y, t.y), 0.f);
                            float area_p = (p.z - p.x) * (p.w - p.y);
                            float area_t = (t.z - t.x) * (t.w - t.y);
                            float uni = area_p + area_t - inter;
                            float iou = inter / (uni + EPSG);
                            float enc = (fmaxf(p.z, t.z) - fminf(p.x, t.x)) *
                                        (fmaxf(p.w, t.w) - fminf(p.y, t.y));
                            float giou = iou - (enc - uni) / (enc + EPSG);
                            loss_sum += 1.f - giou;
                            mcnt++;
                        }
                    }
                    if (lane == F) resolved = true;
                }
            }
        }

        cur_cnt = nxt_cnt; cur_p = nxt_p;
        #pragma unroll
        for (int e = 0; e < CAP; ++e) cur_c[e] = nxt_c[e];
    }

    // cross-lane reduce (fixed order -> deterministic)
    float ls = loss_sum, cs = (float)mcnt;
    #pragma unroll
    for (int off = 32; off >= 1; off >>= 1) {
        ls += __shfl_xor(ls, off);
        cs += __shfl_xor(cs, off);
    }
    if (lane == 0) per_img[b] = (cs > 0.f) ? ls / cs : 0.f;
}

// ---------------------------------------------------------------------------
// Kernel 3: mean over images -> scalar output. Deterministic (no atomics).
// ---------------------------------------------------------------------------
__global__ void reduce_kernel(const float* __restrict__ per_img,
                              float* __restrict__ out)
{
    if (threadIdx.x == 0 && blockIdx.x == 0) {
        float s = 0.f;
        for (int i = 0; i < NB; ++i) s += per_img[i];
        out[0] = s / (float)NB;
    }
}

extern "C" void kernel_launch(void* const* d_in, const int* in_sizes, int n_in,
                              void* d_out, int out_size, void* d_ws, size_t ws_size,
                              hipStream_t stream)
{
    const float4* pred = (const float4*)d_in[0];   // [16,4096,4] f32
    const float4* tgt  = (const float4*)d_in[1];   // [16,512,4]  f32

    char* ws = (char*)d_ws;
    // layout: counts [NROWS] i32 | cands [CAP*NROWS] float2 | per_img [NB] f32
    int*    counts  = (int*)ws;
    size_t  off1    = (size_t)NROWS * sizeof(int);                 // 256 KB
    float2* cands   = (float2*)(ws + off1);
    size_t  off2    = off1 + (size_t)CAP * NROWS * sizeof(float2); // +8 MB
    float*  per_img = (float*)(ws + off2);

    cand_kernel<<<NROWS / 4, 256, 0, stream>>>(pred, tgt, counts, cands);
    scan_kernel<<<NB, 64, 0, stream>>>(pred, tgt, counts, cands, per_img);
    reduce_kernel<<<1, 64, 0, stream>>>(per_img, (float*)d_out);
}

// Round 3
// 156.362 us; speedup vs baseline: 14.1062x; 1.0724x over previous
//
#include <hip/hip_runtime.h>
#include <math.h>

#define NB   16      // batch
#define NM   4096    // preds per image
#define NT   512     // targets per image
#define CAP  16      // max stored candidates per row (overflow -> exact fallback)
#define IOU_THR 0.1f
#define EPSG 1e-7f
#define NROWS (NB*NM)

// ---------------------------------------------------------------------------
// Kernel 1: per pred-row candidate list (targets with IoU > 0.1), ascending j.
// One wave (64 lanes) per row; 8 targets per lane. Candidates stored
// TRANSPOSED: cands[e*NROWS + row] so kernel-2 loads are coalesced.
// ---------------------------------------------------------------------------
__global__ __launch_bounds__(256) void cand_kernel(
    const float4* __restrict__ pred, const float4* __restrict__ tgt,
    int* __restrict__ counts, float2* __restrict__ cands)
{
    int gtid = blockIdx.x * blockDim.x + threadIdx.x;
    int wid  = gtid >> 6;           // global row id in [0, NROWS)
    int lane = threadIdx.x & 63;
    int b = wid >> 12;              // NM = 4096

    float4 p = pred[wid];
    float area_p = (p.z - p.x) * (p.w - p.y);
    const float4* t_img = tgt + b * NT;

    int base = 0;
    #pragma unroll
    for (int pass = 0; pass < NT / 64; ++pass) {
        int j = (pass << 6) + lane;
        float4 t = t_img[j];
        float area_t = (t.z - t.x) * (t.w - t.y);
        float w = fmaxf(fminf(p.z, t.z) - fmaxf(p.x, t.x), 0.f);
        float h = fmaxf(fminf(p.w, t.w) - fmaxf(p.y, t.y), 0.f);
        float inter = w * h;
        float uni   = (area_p + area_t) - inter;   // same association as reference
        float iou   = inter / uni;
        bool q = iou > IOU_THR;
        unsigned long long m = __ballot(q);
        if (q) {
            int off = base + __popcll(m & ((1ull << lane) - 1ull));
            if (off < CAP)
                cands[(size_t)off * NROWS + wid] = make_float2(iou, __int_as_float(j));
        }
        base += __popcll(m);
    }
    if (lane == 0) counts[wid] = base;   // may exceed CAP -> fallback flag
}

// ---------------------------------------------------------------------------
// Kernel 2: window-parallel greedy via auction-to-fixed-point. One wave per
// image; lane r owns row (win*64 + r). claim[j] = min row that ever proposed
// target j (monotone). Committed targets keep their claim -> "claim[j] < row"
// means "used by an earlier row OR held by a smaller concurrent row".
// Fixed point == serial greedy (see proof in journal).
// ---------------------------------------------------------------------------
__global__ __launch_bounds__(64) void scan_kernel(
    const float4* __restrict__ pred, const float4* __restrict__ tgt,
    const int* __restrict__ counts, const float2* __restrict__ cands,
    float* __restrict__ per_img)
{
    __shared__ float4   t_lds[NT];   // 8 KB
    __shared__ unsigned claim[NT];   // 2 KB

    const int b    = blockIdx.x;
    const int lane = threadIdx.x;

    #pragma unroll
    for (int r = 0; r < NT / 64; ++r) {
        t_lds[r * 64 + lane] = tgt[b * NT + r * 64 + lane];
        claim[r * 64 + lane] = 0xFFFFFFFFu;
    }
    __syncthreads();

    float loss_sum  = 0.f;
    int   mcnt      = 0;
    int   used_count = 0;

    // load window 0 into registers (lane = row within window)
    int cur_cnt; float4 cur_p; float2 cur_c[CAP];
    {
        int row = b * NM + lane;
        cur_cnt = counts[row];
        cur_p   = pred[row];
        #pragma unroll
        for (int e = 0; e < CAP; ++e) cur_c[e] = cands[(size_t)e * NROWS + row];
    }

    for (int win = 0; win < NM / 64; ++win) {
        if (used_count == NT) break;   // all targets used: remaining rows invalid

        // prefetch next window; latency hides under the auction
        int nxt_cnt; float4 nxt_p; float2 nxt_c[CAP];
        {
            int w2  = (win + 1 < NM / 64) ? win + 1 : 0;
            int row = b * NM + w2 * 64 + lane;
            nxt_cnt = counts[row];
            nxt_p   = pred[row];
            #pragma unroll
            for (int e = 0; e < CAP; ++e) nxt_c[e] = cands[(size_t)e * NROWS + row];
        }

        const unsigned arow = (unsigned)(win * 64 + lane);  // per-image row id
        bool ovf  = (cur_cnt > CAP);
        bool want = (cur_cnt > 0) && !ovf;   // unresolved, auction-eligible
        bool hold = false;
        int  my_j = -1;

        while (true) {
            unsigned long long om = __ballot(ovf);          // pending overflow rows
            const int F = om ? (__ffsll(om) - 1) : 64;      // segment barrier

            // ---- auction to fixed point among lanes < F ----
            while (true) {
                bool p = want && !hold && (lane < F);
                if (__ballot(p) == 0ull) break;
                int bj = -1;
                if (p) {
                    float bv = -1.f;
                    #pragma unroll
                    for (int e = 0; e < CAP; ++e) {
                        int j = __float_as_int(cur_c[e].y) & (NT - 1);
                        bool ok = (e < cur_cnt) && (claim[j] >= arow);
                        float v = cur_c[e].x;
                        if (ok && v > bv) { bv = v; bj = j; }  // strict >: lowest j on ties
                    }
                    if (bj < 0) want = false;                  // invalid: nothing free
                    else atomicMin(&claim[bj], arow);
                }
                // settle: new proposers check win; holders detect snipes
                int jj = hold ? my_j : bj;
                if (hold || (p && bj >= 0)) {
                    bool w = (claim[jj] == arow);
                    if (w) my_j = jj;
                    hold = w;
                }
            }

            // ---- commit ALL holders (exactly the serial outcome) ----
            if (hold) {
                float4 t = t_lds[my_j];
                float4 p4 = cur_p;
                float inter = fmaxf(fminf(p4.z, t.z) - fmaxf(p4.x, t.x), 0.f) *
                              fmaxf(fminf(p4.w, t.w) - fmaxf(p4.y, t.y), 0.f);
                float area_p = (p4.z - p4.x) * (p4.w - p4.y);
                float area_t = (t.z - t.x) * (t.w - t.y);
                float uni = area_p + area_t - inter;
                float iou = inter / (uni + EPSG);
                float enc = (fmaxf(p4.z, t.z) - fminf(p4.x, t.x)) *
                            (fmaxf(p4.w, t.w) - fminf(p4.y, t.y));
                float giou = iou - (enc - uni) / (enc + EPSG);
                loss_sum += 1.f - giou;
                mcnt++;
            }
            used_count += (int)__popcll(__ballot(hold));
            if (hold) { hold = false; want = false; }

            if (F == 64) break;

            // ---- exact fallback for overflow row F (claim-aware full scan) ----
            {
                float px = __shfl(cur_p.x, F), py = __shfl(cur_p.y, F);
                float pz = __shfl(cur_p.z, F), pw = __shfl(cur_p.w, F);
                float area_p = (pz - px) * (pw - py);
                const unsigned rF = (unsigned)(win * 64 + F);
                float v = -1.f; int bj = NT;
                #pragma unroll
                for (int pass = 0; pass < NT / 64; ++pass) {
                    int j = (pass << 6) + lane;
                    bool freej = (claim[j] > rF);
                    float4 t = t_lds[j];
                    float area_t = (t.z - t.x) * (t.w - t.y);
                    float w = fmaxf(fminf(pz, t.z) - fmaxf(px, t.x), 0.f);
                    float h = fmaxf(fminf(pw, t.w) - fmaxf(py, t.y), 0.f);
                    float inter = w * h;
                    float iou = inter / ((area_p + area_t) - inter);
                    if (freej && iou > v) { v = iou; bj = j; }
                }
                #pragma unroll
                for (int off = 1; off < 64; off <<= 1) {
                    float ov = __shfl_xor(v, off);
                    int   oj = __shfl_xor(bj, off);
                    if (ov > v || (ov == v && oj < bj)) { v = ov; bj = oj; }
                }
                if (v > IOU_THR) {
                    if (lane == 0) claim[bj] = rF;   // mark taken
                    if (lane == F) {
                        float4 t = t_lds[bj];
                        float4 p4 = cur_p;
                        float inter = fmaxf(fminf(p4.z, t.z) - fmaxf(p4.x, t.x), 0.f) *
                                      fmaxf(fminf(p4.w, t.w) - fmaxf(p4.y, t.y), 0.f);
                        float area_p2 = (p4.z - p4.x) * (p4.w - p4.y);
                        float area_t = (t.z - t.x) * (t.w - t.y);
                        float uni = area_p2 + area_t - inter;
                        float iou = inter / (uni + EPSG);
                        float enc = (fmaxf(p4.z, t.z) - fminf(p4.x, t.x)) *
                                    (fmaxf(p4.w, t.w) - fminf(p4.y, t.y));
                        float giou = iou - (enc - uni) / (enc + EPSG);
                        loss_sum += 1.f - giou;
                        mcnt++;
                    }
                    ++used_count;                    // wave-uniform (v,bj broadcast)
                }
                if (lane == F) ovf = false;
            }
        }

        cur_cnt = nxt_cnt; cur_p = nxt_p;
        #pragma unroll
        for (int e = 0; e < CAP; ++e) cur_c[e] = nxt_c[e];
    }

    // cross-lane reduce (fixed order -> deterministic)
    float ls = loss_sum, cs = (float)mcnt;
    #pragma unroll
    for (int off = 32; off >= 1; off >>= 1) {
        ls += __shfl_xor(ls, off);
        cs += __shfl_xor(cs, off);
    }
    if (lane == 0) per_img[b] = (cs > 0.f) ? ls / cs : 0.f;
}

// ---------------------------------------------------------------------------
// Kernel 3: mean over images -> scalar output. Deterministic (no atomics).
// ---------------------------------------------------------------------------
__global__ void reduce_kernel(const float* __restrict__ per_img,
                              float* __restrict__ out)
{
    if (threadIdx.x == 0 && blockIdx.x == 0) {
        float s = 0.f;
        for (int i = 0; i < NB; ++i) s += per_img[i];
        out[0] = s / (float)NB;
    }
}

extern "C" void kernel_launch(void* const* d_in, const int* in_sizes, int n_in,
                              void* d_out, int out_size, void* d_ws, size_t ws_size,
                              hipStream_t stream)
{
    const float4* pred = (const float4*)d_in[0];   // [16,4096,4] f32
    const float4* tgt  = (const float4*)d_in[1];   // [16,512,4]  f32

    char* ws = (char*)d_ws;
    // layout: counts [NROWS] i32 | cands [CAP*NROWS] float2 | per_img [NB] f32
    int*    counts  = (int*)ws;
    size_t  off1    = (size_t)NROWS * sizeof(int);                 // 256 KB
    float2* cands   = (float2*)(ws + off1);
    size_t  off2    = off1 + (size_t)CAP * NROWS * sizeof(float2); // +8 MB
    float*  per_img = (float*)(ws + off2);

    cand_kernel<<<NROWS / 4, 256, 0, stream>>>(pred, tgt, counts, cands);
    scan_kernel<<<NB, 64, 0, stream>>>(pred, tgt, counts, cands, per_img);
    reduce_kernel<<<1, 64, 0, stream>>>(per_img, (float*)d_out);
}

// Round 5
// 119.205 us; speedup vs baseline: 18.5031x; 1.3117x over previous
//
#include <hip/hip_runtime.h>
#include <math.h>

#define NB   16      // batch
#define NM   4096    // preds per image
#define NT   512     // targets per image
#define CAP  16      // max stored candidates per row (overflow -> exact fallback)
#define IOU_THR 0.1f
#define EPSG 1e-7f
#define NROWS (NB*NM)
#define T_AUC 512            // threads per auction block (== NT)
#define RPT   (NM / T_AUC)   // 8 rows per thread, strided ownership

// row status
#define ST_UNRES   0
#define ST_PROP    1
#define ST_HOLD    2
#define ST_MATCHED 3
#define ST_INVALID 4
#define ST_OVF     5

// ---------------------------------------------------------------------------
// Kernel 1: per pred-row candidate list (targets with IoU > 0.1), ascending j.
// One wave per row; 8 targets per lane. Stored TRANSPOSED (e-major) so the
// auction kernel's strided row ownership reads coalesced.
// ---------------------------------------------------------------------------
__global__ __launch_bounds__(256) void cand_kernel(
    const float4* __restrict__ pred, const float4* __restrict__ tgt,
    int* __restrict__ counts, float2* __restrict__ cands)
{
    int gtid = blockIdx.x * blockDim.x + threadIdx.x;
    int wid  = gtid >> 6;           // global row id in [0, NROWS)
    int lane = threadIdx.x & 63;
    int b = wid >> 12;              // NM = 4096

    float4 p = pred[wid];
    float area_p = (p.z - p.x) * (p.w - p.y);
    const float4* t_img = tgt + b * NT;

    int base = 0;
    #pragma unroll
    for (int pass = 0; pass < NT / 64; ++pass) {
        int j = (pass << 6) + lane;
        float4 t = t_img[j];
        float area_t = (t.z - t.x) * (t.w - t.y);
        float w = fmaxf(fminf(p.z, t.z) - fmaxf(p.x, t.x), 0.f);
        float h = fmaxf(fminf(p.w, t.w) - fmaxf(p.y, t.y), 0.f);
        float inter = w * h;
        float uni   = (area_p + area_t) - inter;   // same association as reference
        float iou   = inter / uni;
        bool q = iou > IOU_THR;
        unsigned long long m = __ballot(q);
        if (q) {
            int off = base + __popcll(m & ((1ull << lane) - 1ull));
            if (off < CAP)
                cands[(size_t)off * NROWS + wid] = make_float2(iou, __int_as_float(j));
        }
        base += __popcll(m);
    }
    if (lane == 0) counts[wid] = base;   // may exceed CAP -> overflow flag
}

// ---------------------------------------------------------------------------
// Kernel 2: GLOBAL auction to fixed point, one block (512 thr) per image.
// Thread t owns rows {t, t+512, ...}; claim[j] = min row that ever proposed j
// (monotone decreasing). Fixed point == serial greedy (unique, race-robust).
// Round protocol uses 3 barriers: (A) reset->set, (B) set->read, (C) read->reset.
// ---------------------------------------------------------------------------
__global__ __launch_bounds__(T_AUC) void auction_kernel(
    const float4* __restrict__ pred, const float4* __restrict__ tgt,
    const int* __restrict__ counts, const float2* __restrict__ cands,
    float* __restrict__ per_img)
{
    __shared__ unsigned claim[NT];
    __shared__ int flag;
    __shared__ int ovf_min;
    __shared__ int ovf_res;
    __shared__ float4 ovf_pred;
    __shared__ float rls[T_AUC / 64];
    __shared__ float rcs[T_AUC / 64];
    __shared__ float rvv[T_AUC / 64];
    __shared__ int   rjj[T_AUC / 64];

    const int b = blockIdx.x;
    const int t = threadIdx.x;
    const int gbase = b * NM;

    claim[t] = 0xFFFFFFFFu;             // T_AUC == NT

    int cn[RPT]; int st[RPT]; int mj[RPT];
    #pragma unroll
    for (int k = 0; k < RPT; ++k) {
        int row = t + k * T_AUC;
        int c = counts[gbase + row];
        cn[k] = c;
        st[k] = (c == 0) ? ST_INVALID : (c > CAP ? ST_OVF : ST_UNRES);
        mj[k] = -1;
    }
    __syncthreads();

    while (true) {
        // ---- auction rounds until no proposer ----
        while (true) {
            if (t == 0) flag = 0;
            __syncthreads();                       // A: reset visible before sets
            bool iprop = false;
            #pragma unroll
            for (int k = 0; k < RPT; ++k) {
                unsigned row = (unsigned)(t + k * T_AUC);
                if (st[k] == ST_HOLD && claim[mj[k]] != row) st[k] = ST_UNRES;
                if (st[k] == ST_UNRES) {
                    const float2* cp = cands + gbase + (int)row;
                    int cnk = cn[k];
                    float bv = -1.f; int bj = -1;
                    #pragma unroll
                    for (int e = 0; e < CAP; ++e) {   // predicated loads: one wait
                        float2 c = make_float2(-1.f, 0.f);
                        if (e < cnk) c = cp[(size_t)e * NROWS];
                        int j = __float_as_int(c.y) & (NT - 1);
                        if (e < cnk && claim[j] >= row && c.x > bv) { bv = c.x; bj = j; }
                    }
                    if (bj < 0) st[k] = ST_INVALID;   // claims only decrease: permanent
                    else {
                        atomicMin(&claim[bj], row);
                        mj[k] = bj; st[k] = ST_PROP; iprop = true;
                    }
                }
            }
            if (iprop) flag = 1;                   // benign race: all write 1
            __syncthreads();                       // B: sets + claims visible
            #pragma unroll
            for (int k = 0; k < RPT; ++k) {
                unsigned row = (unsigned)(t + k * T_AUC);
                if (st[k] == ST_PROP)
                    st[k] = (claim[mj[k]] == row) ? ST_HOLD : ST_UNRES;
            }
            int f = flag;                          // every thread reads same value
            __syncthreads();                       // C: reads done before next reset
            if (f == 0) break;                     // uniform exit
        }

        // ---- overflow rows (count > CAP, ~never): exact serial fallback ----
        if (t == 0) ovf_min = 0x7FFFFFFF;
        __syncthreads();
        #pragma unroll
        for (int k = 0; k < RPT; ++k)
            if (st[k] == ST_OVF) atomicMin(&ovf_min, t + k * T_AUC);
        __syncthreads();
        const int rowF = ovf_min;                  // uniform read
        if (rowF == 0x7FFFFFFF) break;             // no overflow pending: done
        #pragma unroll
        for (int k = 0; k < RPT; ++k)
            if (st[k] == ST_OVF && (t + k * T_AUC) == rowF)
                ovf_pred = pred[gbase + rowF];
        __syncthreads();
        {   // cooperative claim-aware argmax over all 512 targets (thread t = target t)
            float4 p4 = ovf_pred;
            float4 tt = tgt[b * NT + t];
            float area_p = (p4.z - p4.x) * (p4.w - p4.y);
            float area_t = (tt.z - tt.x) * (tt.w - tt.y);
            float w = fmaxf(fminf(p4.z, tt.z) - fmaxf(p4.x, tt.x), 0.f);
            float h = fmaxf(fminf(p4.w, tt.w) - fmaxf(p4.y, tt.y), 0.f);
            float inter = w * h;
            float iou = inter / ((area_p + area_t) - inter);
            bool freej = (claim[t] > (unsigned)rowF);  // < rowF final-used; > rowF snipeable
            float v = freej ? iou : -1.f;
            int bj = freej ? t : NT;
            #pragma unroll
            for (int off = 1; off < 64; off <<= 1) {
                float ov = __shfl_xor(v, off);
                int   oj = __shfl_xor(bj, off);
                if (ov > v || (ov == v && oj < bj)) { v = ov; bj = oj; }
            }
            if ((t & 63) == 0) { rvv[t >> 6] = v; rjj[t >> 6] = bj; }
        }
        __syncthreads();
        if (t == 0) {
            float v = rvv[0]; int bj = rjj[0];
            for (int w = 1; w < T_AUC / 64; ++w)
                if (rvv[w] > v || (rvv[w] == v && rjj[w] < bj)) { v = rvv[w]; bj = rjj[w]; }
            if (v > IOU_THR) { ovf_res = bj; claim[bj] = (unsigned)rowF; }  // steal
            else ovf_res = -1;
        }
        __syncthreads();
        #pragma unroll
        for (int k = 0; k < RPT; ++k)
            if (st[k] == ST_OVF && (t + k * T_AUC) == rowF) {
                mj[k] = ovf_res;
                st[k] = (ovf_res >= 0) ? ST_MATCHED : ST_INVALID;
            }
        // loop: auction re-runs; a displaced holder re-enters via the hold-check
    }

    // ---- commit: GIoU for matched rows, deterministic reduction ----
    float ls = 0.f, cs = 0.f;
    #pragma unroll
    for (int k = 0; k < RPT; ++k) {
        if (st[k] == ST_HOLD || st[k] == ST_MATCHED) {
            int row = t + k * T_AUC;
            float4 p4 = pred[gbase + row];
            float4 tt = tgt[b * NT + mj[k]];
            float inter = fmaxf(fminf(p4.z, tt.z) - fmaxf(p4.x, tt.x), 0.f) *
                          fmaxf(fminf(p4.w, tt.w) - fmaxf(p4.y, tt.y), 0.f);
            float area_p = (p4.z - p4.x) * (p4.w - p4.y);
            float area_t = (tt.z - tt.x) * (tt.w - tt.y);
            float uni = area_p + area_t - inter;
            float iou = inter / (uni + EPSG);
            float enc = (fmaxf(p4.z, tt.z) - fminf(p4.x, tt.x)) *
                        (fmaxf(p4.w, tt.w) - fminf(p4.y, tt.y));
            float giou = iou - (enc - uni) / (enc + EPSG);
            ls += 1.f - giou;
            cs += 1.f;
        }
    }
    #pragma unroll
    for (int off = 32; off >= 1; off >>= 1) {
        ls += __shfl_xor(ls, off);
        cs += __shfl_xor(cs, off);
    }
    if ((t & 63) == 0) { rls[t >> 6] = ls; rcs[t >> 6] = cs; }
    __syncthreads();
    if (t == 0) {
        float L = 0.f, C = 0.f;
        for (int w = 0; w < T_AUC / 64; ++w) { L += rls[w]; C += rcs[w]; }
        per_img[b] = (C > 0.f) ? L / C : 0.f;
    }
}

// ---------------------------------------------------------------------------
// Kernel 3: mean over images -> scalar output. Deterministic (no atomics).
// ---------------------------------------------------------------------------
__global__ void reduce_kernel(const float* __restrict__ per_img,
                              float* __restrict__ out)
{
    if (threadIdx.x == 0 && blockIdx.x == 0) {
        float s = 0.f;
        for (int i = 0; i < NB; ++i) s += per_img[i];
        out[0] = s / (float)NB;
    }
}

extern "C" void kernel_launch(void* const* d_in, const int* in_sizes, int n_in,
                              void* d_out, int out_size, void* d_ws, size_t ws_size,
                              hipStream_t stream)
{
    const float4* pred = (const float4*)d_in[0];   // [16,4096,4] f32
    const float4* tgt  = (const float4*)d_in[1];   // [16,512,4]  f32

    char* ws = (char*)d_ws;
    // layout: counts [NROWS] i32 | cands [CAP*NROWS] float2 | per_img [NB] f32
    int*    counts  = (int*)ws;
    size_t  off1    = (size_t)NROWS * sizeof(int);                 // 256 KB
    float2* cands   = (float2*)(ws + off1);
    size_t  off2    = off1 + (size_t)CAP * NROWS * sizeof(float2); // +8 MB
    float*  per_img = (float*)(ws + off2);

    cand_kernel<<<NROWS / 4, 256, 0, stream>>>(pred, tgt, counts, cands);
    auction_kernel<<<NB, T_AUC, 0, stream>>>(pred, tgt, counts, cands, per_img);
    reduce_kernel<<<1, 64, 0, stream>>>(per_img, (float*)d_out);
}